// Round 1
// baseline (212.545 us; speedup 1.0000x reference)
//
#include <hip/hip_runtime.h>

// HierarchicalClassifier: B=16384, D=2048, N_TOP=8, N_CLASS=16
// out[b, t*16+c] = sigmoid(f.top_W[t]+top_b[t]) * softmax_c(f.bottom_W[t,:,c]+bot_b[t,c])
//
// R7: deep software pipeline. R6 prefetched A (HBM, ~900cy) and B (L2, ~200cy)
// one step ahead in one vmcnt queue -> compute's wait on B[ks] drained A[ks]
// issued only ~1 step earlier -> ~300-600cy stall/step (latency-bound, ~35% of
// HBM achievable). Fix: A issued 3 steps ahead (4 named sets bA0..bA3), B issued
// 2 steps ahead (2 named sets, reloaded right after consumption), with B-issue
// preceding A-issue each step so the vmcnt wait for B[s] drains exactly A[s]
// (issued ~900cy earlier, just-in-time) and keeps A[s+1..s+3], B[s+1..s+2] in
// flight. K-loop fully unrolled with literal set indices (SROA-safe per R5
// post-mortem). ~235 VGPR (<256), 2 waves/SIMD, numerics identical to R6.

#define D_DIM 2048
#define NTILE 9          // 144 columns / 16
#define M_ROWS 32        // rows per workgroup (2 row-tiles of 16)

using f32x4 = float __attribute__((ext_vector_type(4)));
using half8 = _Float16 __attribute__((ext_vector_type(8)));
using fp16x2 = __fp16 __attribute__((ext_vector_type(2)));

// Swizzled B layout: S[(((w*16 + ks)*9 + nt)*64 + lane)*8 + j]
//   = W[n = nt*16 + (lane&15)][k = w*512 + ks*32 + (lane>>4)*8 + j]
// W rows 0..7 = top_W, 8..135 = bottom_W[t][:,c] (n-8 = t*16+c), 136..143 = 0.
__global__ void prep_weights(const float* __restrict__ topW,
                             const float* __restrict__ botW,
                             _Float16* __restrict__ S) {
    int idx = blockIdx.x * blockDim.x + threadIdx.x;   // [0, 4*16*9*64)
    if (idx >= 4 * 16 * NTILE * 64) return;
    int lane = idx & 63;
    int tmp  = idx >> 6;          // (w*16+ks)*9 + nt
    int nt   = tmp % NTILE;
    int wks  = tmp / NTILE;       // w*16+ks in [0,64)
    int n     = nt * 16 + (lane & 15);
    int kbase = wks * 32 + (lane >> 4) * 8;

    _Float16 v[8];
    #pragma unroll
    for (int j = 0; j < 8; j++) {
        int k = kbase + j;
        float x = 0.0f;
        if (n < 8) {
            x = topW[n * D_DIM + k];
        } else if (n < 136) {
            int t = (n - 8) >> 4, c = (n - 8) & 15;
            x = botW[(t * D_DIM + k) * 16 + c];
        }
        v[j] = (_Float16)x;
    }
    *(half8*)(S + (size_t)idx * 8) = *(half8*)v;
}

static __device__ __forceinline__ half8 pack_af(f32x4 a, f32x4 b) {
    fp16x2 p0 = __builtin_amdgcn_cvt_pkrtz(a[0], a[1]);
    fp16x2 p1 = __builtin_amdgcn_cvt_pkrtz(a[2], a[3]);
    fp16x2 p2 = __builtin_amdgcn_cvt_pkrtz(b[0], b[1]);
    fp16x2 p3 = __builtin_amdgcn_cvt_pkrtz(b[2], b[3]);
    half8 r;
    r[0] = (_Float16)p0[0]; r[1] = (_Float16)p0[1];
    r[2] = (_Float16)p1[0]; r[3] = (_Float16)p1[1];
    r[4] = (_Float16)p2[0]; r[5] = (_Float16)p2[1];
    r[6] = (_Float16)p3[0]; r[7] = (_Float16)p3[1];
    return r;
}

__global__ __launch_bounds__(256, 2) void hc_fused(
        const float* __restrict__ feat, const _Float16* __restrict__ Bsw,
        const float* __restrict__ top_b, const float* __restrict__ bot_b,
        float* __restrict__ out) {
    __shared__ float red[4][M_ROWS][148];   // [wave][row][ncol(+pad)] = 74 KB

    const int tid  = threadIdx.x;
    const int lane = tid & 63, wave = tid >> 6;
    const int quad = lane >> 4, low = lane & 15;
    const size_t row0 = (size_t)blockIdx.x * M_ROWS;

    // A: lane holds A[m=low][k = quad*8 + j]; this wave's K range = [wave*512, +512)
    const float* A0 = feat + (row0 + low) * D_DIM + wave * 512 + quad * 8;
    const float* A1 = A0 + 16 * D_DIM;
    // B: swizzled fragment stream; per (ks,nt) a contiguous 1KB wave read.
    const _Float16* Bp = Bsw + (size_t)wave * (16 * NTILE * 512) + lane * 8;

    f32x4 acc0[NTILE], acc1[NTILE];
    #pragma unroll
    for (int i = 0; i < NTILE; i++) { acc0[i] = (f32x4)0.0f; acc1[i] = (f32x4)0.0f; }

    // Pipeline register sets: A 4-deep (3 steps ahead), B 2-deep (2 steps ahead,
    // each set reloaded immediately after its consumption).
    half8 bB0[NTILE], bB1[NTILE];
    f32x4 bA0[4], bA1[4], bA2[4], bA3[4];

#define LOAD_B(SET, KS) do {                                               \
        const _Float16* Bn_ = Bp + (size_t)(KS) * NTILE * 512;             \
        _Pragma("unroll")                                                  \
        for (int nt_ = 0; nt_ < NTILE; nt_++)                              \
            SET[nt_] = *(const half8*)(Bn_ + nt_ * 512);                   \
    } while (0)

#define LOAD_A(SET, KS) do {                                               \
        const float* a0_ = A0 + (KS) * 32;                                 \
        const float* a1_ = A1 + (KS) * 32;                                 \
        SET[0] = *(const f32x4*)(a0_);                                     \
        SET[1] = *(const f32x4*)(a0_ + 4);                                 \
        SET[2] = *(const f32x4*)(a1_);                                     \
        SET[3] = *(const f32x4*)(a1_ + 4);                                 \
    } while (0)

#define COMPUTE(ASET, BSET) do {                                           \
        const half8 af0_ = pack_af(ASET[0], ASET[1]);                      \
        const half8 af1_ = pack_af(ASET[2], ASET[3]);                      \
        _Pragma("unroll")                                                  \
        for (int nt_ = 0; nt_ < NTILE; nt_++) {                            \
            acc0[nt_] = __builtin_amdgcn_mfma_f32_16x16x32_f16(            \
                            af0_, BSET[nt_], acc0[nt_], 0, 0, 0);          \
            acc1[nt_] = __builtin_amdgcn_mfma_f32_16x16x32_f16(            \
                            af1_, BSET[nt_], acc1[nt_], 0, 0, 0);          \
        }                                                                  \
    } while (0)

    // Prologue: fill the pipe. Queue: B0 A0 B1 A1 A2
    LOAD_B(bB0, 0);  LOAD_A(bA0, 0);
    LOAD_B(bB1, 1);  LOAD_A(bA1, 1);  LOAD_A(bA2, 2);

    // Steady state, step s: compute s (waits B[s] -> drains exactly A[s]);
    // then issue B[s+2] (into the set just consumed), then A[s+3].
    COMPUTE(bA0, bB0);  LOAD_B(bB0,  2);  LOAD_A(bA3,  3);   // s=0
    COMPUTE(bA1, bB1);  LOAD_B(bB1,  3);  LOAD_A(bA0,  4);   // s=1
    COMPUTE(bA2, bB0);  LOAD_B(bB0,  4);  LOAD_A(bA1,  5);   // s=2
    COMPUTE(bA3, bB1);  LOAD_B(bB1,  5);  LOAD_A(bA2,  6);   // s=3
    COMPUTE(bA0, bB0);  LOAD_B(bB0,  6);  LOAD_A(bA3,  7);   // s=4
    COMPUTE(bA1, bB1);  LOAD_B(bB1,  7);  LOAD_A(bA0,  8);   // s=5
    COMPUTE(bA2, bB0);  LOAD_B(bB0,  8);  LOAD_A(bA1,  9);   // s=6
    COMPUTE(bA3, bB1);  LOAD_B(bB1,  9);  LOAD_A(bA2, 10);   // s=7
    COMPUTE(bA0, bB0);  LOAD_B(bB0, 10);  LOAD_A(bA3, 11);   // s=8
    COMPUTE(bA1, bB1);  LOAD_B(bB1, 11);  LOAD_A(bA0, 12);   // s=9
    COMPUTE(bA2, bB0);  LOAD_B(bB0, 12);  LOAD_A(bA1, 13);   // s=10
    COMPUTE(bA3, bB1);  LOAD_B(bB1, 13);  LOAD_A(bA2, 14);   // s=11
    COMPUTE(bA0, bB0);  LOAD_B(bB0, 14);  LOAD_A(bA3, 15);   // s=12
    COMPUTE(bA1, bB1);  LOAD_B(bB1, 15);                     // s=13
    COMPUTE(bA2, bB0);                                       // s=14
    COMPUTE(bA3, bB1);                                       // s=15

#undef LOAD_B
#undef LOAD_A
#undef COMPUTE

    // C/D layout (measured m89/m91): col = lane&15, row = quad*4 + reg.
    #pragma unroll
    for (int nt = 0; nt < NTILE; nt++) {
        #pragma unroll
        for (int r = 0; r < 4; r++) {
            red[wave][quad * 4 + r][nt * 16 + low]      = acc0[nt][r];
            red[wave][16 + quad * 4 + r][nt * 16 + low] = acc1[nt][r];
        }
    }
    __syncthreads();

    // Epilogue: thread -> (row = tid>>3 in [0,32), top = tid&7). All active.
    const int row = tid >> 3;
    const int top = tid & 7;
    {
        float zt = top_b[top];
        #pragma unroll
        for (int w = 0; w < 4; w++) zt += red[w][row][top];
        const float sig = 1.0f / (1.0f + __expf(-zt));

        float z[16];
        float zmax = -1e30f;
        #pragma unroll
        for (int c = 0; c < 16; c++) {
            float v = bot_b[top * 16 + c];
            #pragma unroll
            for (int w = 0; w < 4; w++) v += red[w][row][8 + top * 16 + c];
            z[c] = v;
            zmax = fmaxf(zmax, v);
        }
        float s = 0.0f;
        #pragma unroll
        for (int c = 0; c < 16; c++) { z[c] = __expf(z[c] - zmax); s += z[c]; }
        const float scale = sig / s;

        float* o = out + (row0 + row) * 128 + top * 16;
        #pragma unroll
        for (int c = 0; c < 16; c += 4) {
            f32x4 v = { z[c] * scale, z[c+1] * scale, z[c+2] * scale, z[c+3] * scale };
            *(f32x4*)(o + c) = v;
        }
    }
}

extern "C" void kernel_launch(void* const* d_in, const int* in_sizes, int n_in,
                              void* d_out, int out_size, void* d_ws, size_t ws_size,
                              hipStream_t stream) {
    const float* feat  = (const float*)d_in[0];   // (16384, 2048)
    const float* topW  = (const float*)d_in[1];   // (8, 2048)
    const float* topB  = (const float*)d_in[2];   // (8,)
    const float* botW  = (const float*)d_in[3];   // (8, 2048, 16)
    const float* botB  = (const float*)d_in[4];   // (8, 16)
    float* out = (float*)d_out;                   // (16384, 128)
    _Float16* Bsw = (_Float16*)d_ws;              // 144*2048 fp16 = 576 KB swizzled

    prep_weights<<<(4 * 16 * NTILE * 64 + 255) / 256, 256, 0, stream>>>(topW, botW, Bsw);
    hc_fused<<<16384 / M_ROWS, 256, 0, stream>>>(feat, Bsw, topB, botB, out);
}